// Round 14
// baseline (229.568 us; speedup 1.0000x reference)
//
#include <hip/hip_runtime.h>
#include <hip/hip_bf16.h>
#include <cmath>

#define R_ 64
#define B_ 4096
#define D_ 512
#define C_ 128

typedef __attribute__((ext_vector_type(8))) short bf16x8;
typedef __attribute__((ext_vector_type(4))) float f32x4;

__device__ __forceinline__ unsigned short f2bf(float f) {
  union { float f; unsigned u; } x; x.f = f;
  unsigned r = (x.u + 0x7FFFu + ((x.u >> 16) & 1u)) >> 16;
  return (unsigned short)r;
}

// ---------------- prep: W[r][d][c] f32 -> W^T[r][c][d] bf16 ----------------
__global__ void prep_w_kernel(const float* __restrict__ W, unsigned short* __restrict__ wt) {
  __shared__ float t[32][33];
  int bx = blockIdx.x;
  int r = bx >> 6;
  int rem = bx & 63;
  int d0 = (rem >> 2) << 5;   // 16 d-tiles of 32
  int c0 = (rem & 3) << 5;    // 4 c-tiles of 32
  int tx = threadIdx.x & 31, ty = threadIdx.x >> 5;  // 32 x 8
  const float* Wr = W + (size_t)r * D_ * C_;
#pragma unroll
  for (int q = 0; q < 4; ++q) {
    int dl = q * 8 + ty;
    t[dl][tx] = Wr[(size_t)(d0 + dl) * C_ + c0 + tx];
  }
  __syncthreads();
  unsigned short* wtr = wt + (size_t)r * C_ * D_;
#pragma unroll
  for (int q = 0; q < 4; ++q) {
    int cl = q * 8 + ty;
    float v = t[tx][cl];                         // transposed read, pad-33 conflict-free
    wtr[(size_t)(c0 + cl) * D_ + d0 + tx] = f2bf(v);
  }
}

// ---------------- prep: (s, -p*s) per (rule, dim) ----------------
__global__ void prep_ps_kernel(const float* __restrict__ proto, const float* __restrict__ var,
                               float* __restrict__ ps) {
  int i = blockIdx.x * 256 + threadIdx.x;          // R*D elements
  float v = fminf(fmaxf(var[i], 1e-4f), 0.1f);
  float s = 1.2011224087864498f / v;
  float2 o; o.x = s; o.y = -proto[i] * s;
  reinterpret_cast<float2*>(ps)[i] = o;
}

// ---------------- antecedent partial + fused x->bf16 emission ----------------
__global__ __launch_bounds__(256, 4) void fs_partial_kernel(
    const float* __restrict__ x, const float* __restrict__ ps,
    float* __restrict__ fire, unsigned short* __restrict__ xw) {
  __shared__ float x_s[16 * 68];
  __shared__ __align__(16) float ps_s[64 * 128];   // [rule][dim*2], XOR-swizzled granules
  const int tid = threadIdx.x;
  const int b0 = blockIdx.x * 16;
  const int dq = blockIdx.y;                       // dims dq*64 .. dq*64+63

  {  // stage x tile: 16 rows x 64 dims
    int row = tid >> 4, c4 = tid & 15;
    float4 v = *reinterpret_cast<const float4*>(&x[(size_t)(b0 + row) * D_ + dq * 64 + c4 * 4]);
    *reinterpret_cast<float4*>(&x_s[row * 68 + c4 * 4]) = v;
  }
#pragma unroll
  for (int k = 0; k < 8; ++k) {  // stage ps tile: 64 rules x 32 granules(16B), swizzled
    int g = tid + k * 256;
    int row = g >> 5, gi = g & 31;
    float4 v = *reinterpret_cast<const float4*>(&ps[(size_t)row * (D_ * 2) + dq * 128 + gi * 4]);
    int gs = gi ^ (row & 31);
    *reinterpret_cast<float4*>((char*)ps_s + row * 512 + (gs << 4)) = v;
  }
  __syncthreads();

  {  // fused prep_x: emit bf16 of this block's x tile (disjoint across grid)
    int row = tid >> 4, c0 = (tid & 15) * 4;
    const float* sp = &x_s[row * 68 + c0];
    ushort4 o;
    o.x = f2bf(sp[0]); o.y = f2bf(sp[1]); o.z = f2bf(sp[2]); o.w = f2bf(sp[3]);
    *reinterpret_cast<ushort4*>(&xw[(size_t)(b0 + row) * D_ + dq * 64 + c0]) = o;
  }

  const int tr = tid & 63;   // rule = lane
  const int tb = tid >> 6;   // wave -> 4 batch rows
  const int s31 = tr & 31;
  const char* pb = (const char*)ps_s + tr * 512;
  float facc[4] = {0.f, 0.f, 0.f, 0.f};

#pragma unroll
  for (int d4 = 0; d4 < 16; ++d4) {
    float4 psa = *reinterpret_cast<const float4*>(pb + ((((d4 * 2) ^ s31)) << 4));
    float4 psb = *reinterpret_cast<const float4*>(pb + ((((d4 * 2 + 1) ^ s31)) << 4));
#pragma unroll
    for (int i = 0; i < 4; ++i) {
      float4 xv = *reinterpret_cast<const float4*>(&x_s[(tb * 4 + i) * 68 + d4 * 4]);
      float u0 = fmaf(xv.x, psa.x, psa.y);
      float u1 = fmaf(xv.y, psa.z, psa.w);
      float u2 = fmaf(xv.z, psb.x, psb.y);
      float u3 = fmaf(xv.w, psb.z, psb.w);
      facc[i] += exp2f(-(u0 * u0)) + exp2f(-(u1 * u1)) +
                 exp2f(-(u2 * u2)) + exp2f(-(u3 * u3));
    }
  }
#pragma unroll
  for (int i = 0; i < 4; ++i)
    atomicAdd(&fire[(size_t)(b0 + tb * 4 + i) * R_ + tr], facc[i]);
}

// ---------------- softmax over rules, in place on fire buffer ----------------
__global__ void softmax_kernel(float* __restrict__ fire) {
  const int b = blockIdx.x * 4 + (threadIdx.x >> 6);
  const int r = threadIdx.x & 63;
  float v = fire[(size_t)b * R_ + r];
  float m = v;
#pragma unroll
  for (int off = 32; off; off >>= 1) m = fmaxf(m, __shfl_xor(m, off, 64));
  float e = exp2f((v - m) * 1.4426950408889634f);
  float s = e;
#pragma unroll
  for (int off = 32; off; off >>= 1) s += __shfl_xor(s, off, 64);
  fire[(size_t)b * R_ + r] = e / s;
}

// ---------------- fused rule-GEMM + relu + fire-weighted combine ----------------
// R13 reg-staging body + DEPTH-2 prefetch (the single variable): loads for tile
// s+2 issue at start of step s into ping-pong regs; tile s+1's regs ds_write at
// end of step s. Each tile's loads get TWO step-bodies in flight.
// BM=128, BN=C=128, BK=64, 4 rules/block. 8 waves (2x4), wave tile 64x32.
__global__ __launch_bounds__(512, 4) void gemm_kernel(
    const unsigned short* __restrict__ xw, const unsigned short* __restrict__ wt,
    const float* __restrict__ fire, const float* __restrict__ bias,
    float* __restrict__ out) {
  __shared__ __align__(16) unsigned short x_s[2][128 * 64];   // 2 x 16 KB
  __shared__ __align__(16) unsigned short w_s[2][128 * 64];   // 2 x 16 KB
  __shared__ float fire_s[128 * 4];
  __shared__ float bias_s[4 * 128];

  const int tid = threadIdx.x;       // 0..511
  const int f = blockIdx.x;          // 0..511 (XCD-aware decode, neutral but kept)
  const int xcd = f & 7;
  const int idx = f >> 3;
  const int rg = 2 * xcd + (idx & 1);
  const int bm = idx >> 1;
  const int b0 = bm * 128;

  {
    int row = tid >> 2, g = tid & 3;
    fire_s[tid] = fire[(size_t)(b0 + row) * R_ + rg * 4 + g];
    bias_s[tid] = bias[rg * 4 * C_ + tid];
  }

  const int wid = tid >> 6, lane = tid & 63;
  const int wm = wid >> 2, wn = wid & 3;           // 2 x 4 wave grid, wave tile 64x32
  const int l16 = lane & 15, lhi = lane >> 4;

  int offA[4][2], offB[2][2];
#pragma unroll
  for (int m = 0; m < 4; ++m) {
    int row = wm * 64 + m * 16 + l16;
#pragma unroll
    for (int ks = 0; ks < 2; ++ks)
      offA[m][ks] = row * 128 + (((ks * 4 + lhi) ^ (row & 7)) << 4);
  }
#pragma unroll
  for (int n = 0; n < 2; ++n) {
    int row = wn * 32 + n * 16 + l16;
#pragma unroll
    for (int ks = 0; ks < 2; ++ks)
      offB[n][ks] = row * 128 + (((ks * 4 + lhi) ^ (row & 7)) << 4);
  }

  int a_goff[2], a_ldst[2], b_goff[2], b_ldst[2];
#pragma unroll
  for (int q = 0; q < 2; ++q) {
    int ch = q * 512 + tid;
    int row = ch >> 3, g = ch & 7;
    a_goff[q] = row * D_ + g * 8;
    a_ldst[q] = row * 128 + ((g ^ (row & 7)) << 4);
    b_goff[q] = row * D_ + g * 8;
    b_ldst[q] = row * 128 + ((g ^ (row & 7)) << 4);
  }

  const unsigned short* xsrc = xw + (size_t)b0 * D_;
  const unsigned short* wbase = wt + (size_t)(rg * 4) * C_ * D_;

  float tot[4][2][4];
#pragma unroll
  for (int m = 0; m < 4; ++m)
#pragma unroll
    for (int n = 0; n < 2; ++n)
#pragma unroll
      for (int j = 0; j < 4; ++j) tot[m][n][j] = 0.f;

  f32x4 acc[4][2];
  uint4 pa[2][2], pb[2][2];   // [parity][chunk] staging regs

  auto issue = [&](int par, int s) {   // issue tile s loads into parity slot
    const unsigned short* xs = xsrc + (s & 7) * 64;
    const unsigned short* ws = wbase + (size_t)(s >> 3) * C_ * D_ + (s & 7) * 64;
#pragma unroll
    for (int q = 0; q < 2; ++q) {
      pa[par][q] = *reinterpret_cast<const uint4*>(xs + a_goff[q]);
      pb[par][q] = *reinterpret_cast<const uint4*>(ws + b_goff[q]);
    }
  };
  auto commit = [&](int par, int buf) {   // ds_write parity slot -> LDS buffer
#pragma unroll
    for (int q = 0; q < 2; ++q) {
      *reinterpret_cast<uint4*>((char*)x_s[buf] + a_ldst[q]) = pa[par][q];
      *reinterpret_cast<uint4*>((char*)w_s[buf] + b_ldst[q]) = pb[par][q];
    }
  };

  // prologue: tile0 -> p0 -> LDS buf0; tile1 -> p1 (stays in regs)
  issue(0, 0);
  issue(1, 1);
  commit(0, 0);
  __syncthreads();

  // step body as macro-lambda; PAR is compile-time via 2x-unrolled loop
  auto step = [&](int s, int par) {
    const int g = s >> 3, kk = s & 7;
    if (kk == 0) {
#pragma unroll
      for (int m = 0; m < 4; ++m)
#pragma unroll
        for (int n = 0; n < 2; ++n)
          acc[m][n] = f32x4{0.f, 0.f, 0.f, 0.f};
    }
    if (s + 2 < 32) issue(par, s + 2);     // depth-2: 2 step-bodies in flight
    const char* xb = (const char*)x_s[s & 1];
    const char* wb = (const char*)w_s[s & 1];
#pragma unroll
    for (int ks = 0; ks < 2; ++ks) {
      bf16x8 av[4], bv[2];
#pragma unroll
      for (int m = 0; m < 4; ++m)
        av[m] = *reinterpret_cast<const bf16x8*>(xb + offA[m][ks]);
#pragma unroll
      for (int n = 0; n < 2; ++n)
        bv[n] = *reinterpret_cast<const bf16x8*>(wb + offB[n][ks]);
#pragma unroll
      for (int m = 0; m < 4; ++m)
#pragma unroll
        for (int n = 0; n < 2; ++n)
          acc[m][n] = __builtin_amdgcn_mfma_f32_16x16x32_bf16(av[m], bv[n], acc[m][n], 0, 0, 0);
    }
    if (kk == 7) {
#pragma unroll
      for (int m = 0; m < 4; ++m)
#pragma unroll
        for (int n = 0; n < 2; ++n) {
          int col = wn * 32 + n * 16 + l16;
          float bi = bias_s[g * 128 + col];
#pragma unroll
          for (int j = 0; j < 4; ++j) {
            int rowl = wm * 64 + m * 16 + lhi * 4 + j;
            float v = acc[m][n][j] + bi;
            v = fmaxf(v, 0.f);
            tot[m][n][j] += v * fire_s[rowl * 4 + g];
          }
        }
    }
    if (s + 1 < 32) commit(par ^ 1, (s + 1) & 1);  // write tile s+1 (issued at s-1)
    __syncthreads();
  };

  for (int s2 = 0; s2 < 16; ++s2) {   // 2x unrolled: parity compile-time
    step(2 * s2, 0);
    step(2 * s2 + 1, 1);
  }

#pragma unroll
  for (int m = 0; m < 4; ++m)
#pragma unroll
    for (int n = 0; n < 2; ++n) {
      int col = wn * 32 + n * 16 + l16;
#pragma unroll
      for (int j = 0; j < 4; ++j) {
        int rowl = wm * 64 + m * 16 + lhi * 4 + j;
        atomicAdd(&out[(size_t)(b0 + rowl) * C_ + col], tot[m][n][j]);
      }
    }
}

extern "C" void kernel_launch(void* const* d_in, const int* in_sizes, int n_in,
                              void* d_out, int out_size, void* d_ws, size_t ws_size,
                              hipStream_t stream) {
  const float* x     = (const float*)d_in[0];
  const float* proto = (const float*)d_in[1];
  const float* var   = (const float*)d_in[2];
  const float* W     = (const float*)d_in[3];
  const float* bias  = (const float*)d_in[4];
  float* out  = (float*)d_out;
  float* fire = out + (size_t)B_ * C_;   // second output region (also fs_ini accumulator)

  const size_t WS_X  = (size_t)B_ * D_ * sizeof(unsigned short);       // 4 MiB
  const size_t WS_WT = (size_t)R_ * C_ * D_ * sizeof(unsigned short);  // 8 MiB
  const size_t WS_PS = (size_t)R_ * D_ * 2 * sizeof(float);            // 256 KiB
  if (ws_size < WS_X + WS_WT + WS_PS) return;  // insufficient scratch -> visible failure

  unsigned short* xw  = (unsigned short*)d_ws;
  unsigned short* wtp = (unsigned short*)((char*)d_ws + WS_X);
  float*          ps  = (float*)((char*)d_ws + WS_X + WS_WT);

  // zero BOTH output regions: out accumulates gemm atomics, fire accumulates fs partials
  hipMemsetAsync(d_out, 0, (size_t)out_size * sizeof(float), stream);
  prep_w_kernel<<<dim3(R_ * 64), dim3(256), 0, stream>>>(W, wtp);
  prep_ps_kernel<<<dim3(R_ * D_ / 256), dim3(256), 0, stream>>>(proto, var, ps);
  fs_partial_kernel<<<dim3(B_ / 16, 8), dim3(256), 0, stream>>>(x, ps, fire, xw);
  softmax_kernel<<<dim3(B_ / 4), dim3(256), 0, stream>>>(fire);
  gemm_kernel<<<dim3(512), dim3(512), 0, stream>>>(xw, wtp, fire, bias, out);
}

// Round 15
// 218.448 us; speedup vs baseline: 1.0509x; 1.0509x over previous
//
#include <hip/hip_runtime.h>
#include <hip/hip_bf16.h>
#include <cmath>

#define R_ 64
#define B_ 4096
#define D_ 512
#define C_ 128

typedef __attribute__((ext_vector_type(8))) short bf16x8;
typedef __attribute__((ext_vector_type(4))) float f32x4;

__device__ __forceinline__ unsigned short f2bf(float f) {
  union { float f; unsigned u; } x; x.f = f;
  unsigned r = (x.u + 0x7FFFu + ((x.u >> 16) & 1u)) >> 16;
  return (unsigned short)r;
}

// ---------------- prep: W[r][d][c] f32 -> W^T[r][c][d] bf16 ----------------
__global__ void prep_w_kernel(const float* __restrict__ W, unsigned short* __restrict__ wt) {
  __shared__ float t[32][33];
  int bx = blockIdx.x;
  int r = bx >> 6;
  int rem = bx & 63;
  int d0 = (rem >> 2) << 5;   // 16 d-tiles of 32
  int c0 = (rem & 3) << 5;    // 4 c-tiles of 32
  int tx = threadIdx.x & 31, ty = threadIdx.x >> 5;  // 32 x 8
  const float* Wr = W + (size_t)r * D_ * C_;
#pragma unroll
  for (int q = 0; q < 4; ++q) {
    int dl = q * 8 + ty;
    t[dl][tx] = Wr[(size_t)(d0 + dl) * C_ + c0 + tx];
  }
  __syncthreads();
  unsigned short* wtr = wt + (size_t)r * C_ * D_;
#pragma unroll
  for (int q = 0; q < 4; ++q) {
    int cl = q * 8 + ty;
    float v = t[tx][cl];                         // transposed read, pad-33 conflict-free
    wtr[(size_t)(c0 + cl) * D_ + d0 + tx] = f2bf(v);
  }
}

// ---------------- prep: (s, -p*s) per (rule, dim) ----------------
__global__ void prep_ps_kernel(const float* __restrict__ proto, const float* __restrict__ var,
                               float* __restrict__ ps) {
  int i = blockIdx.x * 256 + threadIdx.x;          // R*D elements
  float v = fminf(fmaxf(var[i], 1e-4f), 0.1f);
  float s = 1.2011224087864498f / v;
  float2 o; o.x = s; o.y = -proto[i] * s;
  reinterpret_cast<float2*>(ps)[i] = o;
}

// ---------------- antecedent partial + fused x->bf16 emission ----------------
__global__ __launch_bounds__(256, 4) void fs_partial_kernel(
    const float* __restrict__ x, const float* __restrict__ ps,
    float* __restrict__ fire, unsigned short* __restrict__ xw) {
  __shared__ float x_s[16 * 68];
  __shared__ __align__(16) float ps_s[64 * 128];   // [rule][dim*2], XOR-swizzled granules
  const int tid = threadIdx.x;
  const int b0 = blockIdx.x * 16;
  const int dq = blockIdx.y;                       // dims dq*64 .. dq*64+63

  {  // stage x tile: 16 rows x 64 dims
    int row = tid >> 4, c4 = tid & 15;
    float4 v = *reinterpret_cast<const float4*>(&x[(size_t)(b0 + row) * D_ + dq * 64 + c4 * 4]);
    *reinterpret_cast<float4*>(&x_s[row * 68 + c4 * 4]) = v;
  }
#pragma unroll
  for (int k = 0; k < 8; ++k) {  // stage ps tile: 64 rules x 32 granules(16B), swizzled
    int g = tid + k * 256;
    int row = g >> 5, gi = g & 31;
    float4 v = *reinterpret_cast<const float4*>(&ps[(size_t)row * (D_ * 2) + dq * 128 + gi * 4]);
    int gs = gi ^ (row & 31);
    *reinterpret_cast<float4*>((char*)ps_s + row * 512 + (gs << 4)) = v;
  }
  __syncthreads();

  {  // fused prep_x: emit bf16 of this block's x tile (disjoint across grid)
    int row = tid >> 4, c0 = (tid & 15) * 4;
    const float* sp = &x_s[row * 68 + c0];
    ushort4 o;
    o.x = f2bf(sp[0]); o.y = f2bf(sp[1]); o.z = f2bf(sp[2]); o.w = f2bf(sp[3]);
    *reinterpret_cast<ushort4*>(&xw[(size_t)(b0 + row) * D_ + dq * 64 + c0]) = o;
  }

  const int tr = tid & 63;   // rule = lane
  const int tb = tid >> 6;   // wave -> 4 batch rows
  const int s31 = tr & 31;
  const char* pb = (const char*)ps_s + tr * 512;
  float facc[4] = {0.f, 0.f, 0.f, 0.f};

#pragma unroll
  for (int d4 = 0; d4 < 16; ++d4) {
    float4 psa = *reinterpret_cast<const float4*>(pb + ((((d4 * 2) ^ s31)) << 4));
    float4 psb = *reinterpret_cast<const float4*>(pb + ((((d4 * 2 + 1) ^ s31)) << 4));
#pragma unroll
    for (int i = 0; i < 4; ++i) {
      float4 xv = *reinterpret_cast<const float4*>(&x_s[(tb * 4 + i) * 68 + d4 * 4]);
      float u0 = fmaf(xv.x, psa.x, psa.y);
      float u1 = fmaf(xv.y, psa.z, psa.w);
      float u2 = fmaf(xv.z, psb.x, psb.y);
      float u3 = fmaf(xv.w, psb.z, psb.w);
      facc[i] += exp2f(-(u0 * u0)) + exp2f(-(u1 * u1)) +
                 exp2f(-(u2 * u2)) + exp2f(-(u3 * u3));
    }
  }
#pragma unroll
  for (int i = 0; i < 4; ++i)
    atomicAdd(&fire[(size_t)(b0 + tb * 4 + i) * R_ + tr], facc[i]);
}

// ---------------- softmax over rules, in place on fire buffer ----------------
__global__ void softmax_kernel(float* __restrict__ fire) {
  const int b = blockIdx.x * 4 + (threadIdx.x >> 6);
  const int r = threadIdx.x & 63;
  float v = fire[(size_t)b * R_ + r];
  float m = v;
#pragma unroll
  for (int off = 32; off; off >>= 1) m = fmaxf(m, __shfl_xor(m, off, 64));
  float e = exp2f((v - m) * 1.4426950408889634f);
  float s = e;
#pragma unroll
  for (int off = 32; off; off >>= 1) s += __shfl_xor(s, off, 64);
  fire[(size_t)b * R_ + r] = e / s;
}

// ---------------- fused rule-GEMM + relu + fire-weighted combine ----------------
// R13 reg-staging body + depth-2 prefetch with FORCED-STATIC parity:
// separate named slot arrays (pa0/pb0, pa1/pb1) touched only via macros with
// LITERAL parity tokens; loop body written out 2x with literal parities.
// (R14's runtime-par lambda spilled to scratch — rule #20.)
// Tile t: issued at step t-2 into slot t&1; committed to buf[t&1] end of step t-1.
// BM=128, BN=C=128, BK=64, 4 rules/block. 8 waves (2x4), wave tile 64x32.
__global__ __launch_bounds__(512, 4) void gemm_kernel(
    const unsigned short* __restrict__ xw, const unsigned short* __restrict__ wt,
    const float* __restrict__ fire, const float* __restrict__ bias,
    float* __restrict__ out) {
  __shared__ __align__(16) unsigned short x_s[2][128 * 64];   // 2 x 16 KB
  __shared__ __align__(16) unsigned short w_s[2][128 * 64];   // 2 x 16 KB
  __shared__ float fire_s[128 * 4];
  __shared__ float bias_s[4 * 128];

  const int tid = threadIdx.x;       // 0..511
  const int f = blockIdx.x;          // 0..511 (XCD-aware decode, neutral but kept)
  const int xcd = f & 7;
  const int idx = f >> 3;
  const int rg = 2 * xcd + (idx & 1);
  const int bm = idx >> 1;
  const int b0 = bm * 128;

  {
    int row = tid >> 2, g = tid & 3;
    fire_s[tid] = fire[(size_t)(b0 + row) * R_ + rg * 4 + g];
    bias_s[tid] = bias[rg * 4 * C_ + tid];
  }

  const int wid = tid >> 6, lane = tid & 63;
  const int wm = wid >> 2, wn = wid & 3;           // 2 x 4 wave grid, wave tile 64x32
  const int l16 = lane & 15, lhi = lane >> 4;

  int offA[4][2], offB[2][2];
#pragma unroll
  for (int m = 0; m < 4; ++m) {
    int row = wm * 64 + m * 16 + l16;
#pragma unroll
    for (int ks = 0; ks < 2; ++ks)
      offA[m][ks] = row * 128 + (((ks * 4 + lhi) ^ (row & 7)) << 4);
  }
#pragma unroll
  for (int n = 0; n < 2; ++n) {
    int row = wn * 32 + n * 16 + l16;
#pragma unroll
    for (int ks = 0; ks < 2; ++ks)
      offB[n][ks] = row * 128 + (((ks * 4 + lhi) ^ (row & 7)) << 4);
  }

  int a_goff[2], a_ldst[2], b_goff[2], b_ldst[2];
#pragma unroll
  for (int q = 0; q < 2; ++q) {
    int ch = q * 512 + tid;
    int row = ch >> 3, g = ch & 7;
    a_goff[q] = row * D_ + g * 8;
    a_ldst[q] = row * 128 + ((g ^ (row & 7)) << 4);
    b_goff[q] = row * D_ + g * 8;
    b_ldst[q] = row * 128 + ((g ^ (row & 7)) << 4);
  }

  const unsigned short* xsrc = xw + (size_t)b0 * D_;
  const unsigned short* wbase = wt + (size_t)(rg * 4) * C_ * D_;

  float tot[4][2][4];
#pragma unroll
  for (int m = 0; m < 4; ++m)
#pragma unroll
    for (int n = 0; n < 2; ++n)
#pragma unroll
      for (int j = 0; j < 4; ++j) tot[m][n][j] = 0.f;

  f32x4 acc[4][2];

  // two staging slots, STATICALLY addressed only via literal-parity macros
  uint4 pa0[2], pb0[2], pa1[2], pb1[2];

#define ISSUE(PAR, S)                                                          \
  do {                                                                         \
    const unsigned short* xs_ = xsrc + ((S) & 7) * 64;                         \
    const unsigned short* ws_ = wbase + (size_t)((S) >> 3) * C_ * D_ + ((S) & 7) * 64; \
    _Pragma("unroll")                                                          \
    for (int q = 0; q < 2; ++q) {                                              \
      pa##PAR[q] = *reinterpret_cast<const uint4*>(xs_ + a_goff[q]);           \
      pb##PAR[q] = *reinterpret_cast<const uint4*>(ws_ + b_goff[q]);           \
    }                                                                          \
  } while (0)

#define COMMIT(PAR, BUF)                                                       \
  do {                                                                         \
    _Pragma("unroll")                                                          \
    for (int q = 0; q < 2; ++q) {                                              \
      *reinterpret_cast<uint4*>((char*)x_s[BUF] + a_ldst[q]) = pa##PAR[q];     \
      *reinterpret_cast<uint4*>((char*)w_s[BUF] + b_ldst[q]) = pb##PAR[q];     \
    }                                                                          \
  } while (0)

#define COMPUTE(S, BUF)                                                        \
  do {                                                                         \
    const int g_ = (S) >> 3, kk_ = (S) & 7;                                    \
    if (kk_ == 0) {                                                            \
      _Pragma("unroll") for (int m = 0; m < 4; ++m)                            \
        _Pragma("unroll") for (int n = 0; n < 2; ++n)                          \
          acc[m][n] = f32x4{0.f, 0.f, 0.f, 0.f};                               \
    }                                                                          \
    const char* xb_ = (const char*)x_s[BUF];                                   \
    const char* wb_ = (const char*)w_s[BUF];                                   \
    _Pragma("unroll")                                                          \
    for (int ks = 0; ks < 2; ++ks) {                                           \
      bf16x8 av[4], bv[2];                                                     \
      _Pragma("unroll") for (int m = 0; m < 4; ++m)                            \
        av[m] = *reinterpret_cast<const bf16x8*>(xb_ + offA[m][ks]);           \
      _Pragma("unroll") for (int n = 0; n < 2; ++n)                            \
        bv[n] = *reinterpret_cast<const bf16x8*>(wb_ + offB[n][ks]);           \
      _Pragma("unroll") for (int m = 0; m < 4; ++m)                            \
        _Pragma("unroll") for (int n = 0; n < 2; ++n)                          \
          acc[m][n] = __builtin_amdgcn_mfma_f32_16x16x32_bf16(av[m], bv[n], acc[m][n], 0, 0, 0); \
    }                                                                          \
    if (kk_ == 7) {                                                            \
      _Pragma("unroll") for (int m = 0; m < 4; ++m)                            \
        _Pragma("unroll") for (int n = 0; n < 2; ++n) {                        \
          int col = wn * 32 + n * 16 + l16;                                    \
          float bi = bias_s[g_ * 128 + col];                                   \
          _Pragma("unroll") for (int j = 0; j < 4; ++j) {                      \
            int rowl = wm * 64 + m * 16 + lhi * 4 + j;                         \
            float v = acc[m][n][j] + bi;                                       \
            v = fmaxf(v, 0.f);                                                 \
            tot[m][n][j] += v * fire_s[rowl * 4 + g_];                         \
          }                                                                    \
        }                                                                      \
    }                                                                          \
  } while (0)

  // prologue: tile0 -> slot0 -> buf0; tile1 -> slot1 (stays in regs)
  ISSUE(0, 0);
  ISSUE(1, 1);
  COMMIT(0, 0);
  __syncthreads();

  for (int s2 = 0; s2 < 16; ++s2) {
    const int s = 2 * s2;
    // ---- even step s: compute buf0; issue tile s+2 -> slot0; commit tile s+1 (slot1 -> buf1)
    if (s + 2 < 32) ISSUE(0, s + 2);
    COMPUTE(s, 0);
    if (s + 1 < 32) COMMIT(1, 1);
    __syncthreads();
    // ---- odd step s+1: compute buf1; issue tile s+3 -> slot1; commit tile s+2 (slot0 -> buf0)
    if (s + 3 < 32) ISSUE(1, s + 3);
    COMPUTE(s + 1, 1);
    if (s + 2 < 32) COMMIT(0, 0);
    __syncthreads();
  }

#undef ISSUE
#undef COMMIT
#undef COMPUTE

#pragma unroll
  for (int m = 0; m < 4; ++m)
#pragma unroll
    for (int n = 0; n < 2; ++n) {
      int col = wn * 32 + n * 16 + l16;
#pragma unroll
      for (int j = 0; j < 4; ++j) {
        int rowl = wm * 64 + m * 16 + lhi * 4 + j;
        atomicAdd(&out[(size_t)(b0 + rowl) * C_ + col], tot[m][n][j]);
      }
    }
}

extern "C" void kernel_launch(void* const* d_in, const int* in_sizes, int n_in,
                              void* d_out, int out_size, void* d_ws, size_t ws_size,
                              hipStream_t stream) {
  const float* x     = (const float*)d_in[0];
  const float* proto = (const float*)d_in[1];
  const float* var   = (const float*)d_in[2];
  const float* W     = (const float*)d_in[3];
  const float* bias  = (const float*)d_in[4];
  float* out  = (float*)d_out;
  float* fire = out + (size_t)B_ * C_;   // second output region (also fs_ini accumulator)

  const size_t WS_X  = (size_t)B_ * D_ * sizeof(unsigned short);       // 4 MiB
  const size_t WS_WT = (size_t)R_ * C_ * D_ * sizeof(unsigned short);  // 8 MiB
  const size_t WS_PS = (size_t)R_ * D_ * 2 * sizeof(float);            // 256 KiB
  if (ws_size < WS_X + WS_WT + WS_PS) return;  // insufficient scratch -> visible failure

  unsigned short* xw  = (unsigned short*)d_ws;
  unsigned short* wtp = (unsigned short*)((char*)d_ws + WS_X);
  float*          ps  = (float*)((char*)d_ws + WS_X + WS_WT);

  // zero BOTH output regions: out accumulates gemm atomics, fire accumulates fs partials
  hipMemsetAsync(d_out, 0, (size_t)out_size * sizeof(float), stream);
  prep_w_kernel<<<dim3(R_ * 64), dim3(256), 0, stream>>>(W, wtp);
  prep_ps_kernel<<<dim3(R_ * D_ / 256), dim3(256), 0, stream>>>(proto, var, ps);
  fs_partial_kernel<<<dim3(B_ / 16, 8), dim3(256), 0, stream>>>(x, ps, fire, xw);
  softmax_kernel<<<dim3(B_ / 4), dim3(256), 0, stream>>>(fire);
  gemm_kernel<<<dim3(512), dim3(512), 0, stream>>>(xw, wtp, fire, bias, out);
}

// Round 16
// 146.833 us; speedup vs baseline: 1.5635x; 1.4877x over previous
//
#include <hip/hip_runtime.h>
#include <hip/hip_bf16.h>
#include <cmath>

#define R_ 64
#define B_ 4096
#define D_ 512
#define C_ 128

typedef __attribute__((ext_vector_type(8))) short bf16x8;
typedef __attribute__((ext_vector_type(4))) float f32x4;

__device__ __forceinline__ unsigned short f2bf(float f) {
  union { float f; unsigned u; } x; x.f = f;
  unsigned r = (x.u + 0x7FFFu + ((x.u >> 16) & 1u)) >> 16;
  return (unsigned short)r;
}

// ---------------- prep: W f32 -> frag-native bf16 ----------------
// wf[((r*8+nt)*16 + kc)*512 + lane*8 + e] = W[r][kc*32 + (lane>>4)*8 + e][nt*16 + (lane&15)]
// One B-frag (16 cols x 32 k) = contiguous 1 KB. (Layout validated R10/R11.)
__global__ __launch_bounds__(256) void prep_wf_kernel(const float* __restrict__ W,
                                                      unsigned short* __restrict__ wf) {
  __shared__ float s[32][132];
  const int kc = blockIdx.x;            // 0..15
  const int r = blockIdx.y;             // 0..63
  const int t = threadIdx.x;
#pragma unroll
  for (int p = 0; p < 4; ++p) {         // stage 32 d-rows x 128 c
    int idx = p * 256 + t;              // 1024 float4
    int row = idx >> 5, c4 = idx & 31;
    float4 v = *reinterpret_cast<const float4*>(
        &W[((size_t)r * D_ + kc * 32 + row) * C_ + c4 * 4]);
    *reinterpret_cast<float4*>(&s[row][c4 * 4]) = v;
  }
  __syncthreads();
  const int lane = t & 63, l16 = lane & 15, lhi = lane >> 4;
#pragma unroll
  for (int p = 0; p < 2; ++p) {
    int nt = (t >> 6) + p * 4;          // 0..7
    unsigned short o[8];
#pragma unroll
    for (int e = 0; e < 8; ++e) o[e] = f2bf(s[lhi * 8 + e][nt * 16 + l16]);
    *reinterpret_cast<bf16x8*>(wf + ((size_t)((r * 8 + nt) * 16 + kc)) * 512 + lane * 8) =
        *reinterpret_cast<bf16x8*>(o);
  }
}

// ---------------- prep: (s, -p*s) per (rule, dim) ----------------
__global__ void prep_ps_kernel(const float* __restrict__ proto, const float* __restrict__ var,
                               float* __restrict__ ps) {
  int i = blockIdx.x * 256 + threadIdx.x;          // R*D elements
  float v = fminf(fmaxf(var[i], 1e-4f), 0.1f);
  float s = 1.2011224087864498f / v;
  float2 o; o.x = s; o.y = -proto[i] * s;
  reinterpret_cast<float2*>(ps)[i] = o;
}

// ---------------- antecedent partial + fused x->frag-native bf16 emission ----------------
// Block (bx, dq) covers x rows bx*16..+15 (= m-tile bx), dims dq*64..+63 (= kc dq*2, dq*2+1).
// Emits xf[(bx*16 + kc)*512 + lane*8 + e] = x[bx*16 + (lane&15)][kc*32 + (lane>>4)*8 + e].
__global__ __launch_bounds__(256, 4) void fs_partial_kernel(
    const float* __restrict__ x, const float* __restrict__ ps,
    float* __restrict__ fire, unsigned short* __restrict__ xf) {
  __shared__ float x_s[16 * 68];
  __shared__ __align__(16) float ps_s[64 * 128];   // [rule][dim*2], XOR-swizzled granules
  const int tid = threadIdx.x;
  const int b0 = blockIdx.x * 16;
  const int dq = blockIdx.y;                       // dims dq*64 .. dq*64+63

  {  // stage x tile: 16 rows x 64 dims
    int row = tid >> 4, c4 = tid & 15;
    float4 v = *reinterpret_cast<const float4*>(&x[(size_t)(b0 + row) * D_ + dq * 64 + c4 * 4]);
    *reinterpret_cast<float4*>(&x_s[row * 68 + c4 * 4]) = v;
  }
#pragma unroll
  for (int k = 0; k < 8; ++k) {  // stage ps tile: 64 rules x 32 granules(16B), swizzled
    int g = tid + k * 256;
    int row = g >> 5, gi = g & 31;
    float4 v = *reinterpret_cast<const float4*>(&ps[(size_t)row * (D_ * 2) + dq * 128 + gi * 4]);
    int gs = gi ^ (row & 31);
    *reinterpret_cast<float4*>((char*)ps_s + row * 512 + (gs << 4)) = v;
  }
  __syncthreads();

  {  // fused frag-native bf16 emission (disjoint coverage across grid)
    int kcl = tid >> 7;                 // 0..1
    int lane = (tid >> 1) & 63;
    int epair = tid & 1;
    int row = lane & 15, lhi = lane >> 4;
    const float* sp = &x_s[row * 68 + kcl * 32 + lhi * 8 + epair * 4];
    ushort4 o;
    o.x = f2bf(sp[0]); o.y = f2bf(sp[1]); o.z = f2bf(sp[2]); o.w = f2bf(sp[3]);
    *reinterpret_cast<ushort4*>(
        xf + ((size_t)(blockIdx.x * 16 + dq * 2 + kcl)) * 512 + lane * 8 + epair * 4) = o;
  }

  const int tr = tid & 63;   // rule = lane
  const int tb = tid >> 6;   // wave -> 4 batch rows
  const int s31 = tr & 31;
  const char* pb = (const char*)ps_s + tr * 512;
  float facc[4] = {0.f, 0.f, 0.f, 0.f};

#pragma unroll
  for (int d4 = 0; d4 < 16; ++d4) {
    float4 psa = *reinterpret_cast<const float4*>(pb + ((((d4 * 2) ^ s31)) << 4));
    float4 psb = *reinterpret_cast<const float4*>(pb + ((((d4 * 2 + 1) ^ s31)) << 4));
#pragma unroll
    for (int i = 0; i < 4; ++i) {
      float4 xv = *reinterpret_cast<const float4*>(&x_s[(tb * 4 + i) * 68 + d4 * 4]);
      float u0 = fmaf(xv.x, psa.x, psa.y);
      float u1 = fmaf(xv.y, psa.z, psa.w);
      float u2 = fmaf(xv.z, psb.x, psb.y);
      float u3 = fmaf(xv.w, psb.z, psb.w);
      facc[i] += exp2f(-(u0 * u0)) + exp2f(-(u1 * u1)) +
                 exp2f(-(u2 * u2)) + exp2f(-(u3 * u3));
    }
  }
#pragma unroll
  for (int i = 0; i < 4; ++i)
    atomicAdd(&fire[(size_t)(b0 + tb * 4 + i) * R_ + tr], facc[i]);
}

// ---------------- softmax over rules, in place on fire buffer ----------------
__global__ void softmax_kernel(float* __restrict__ fire) {
  const int b = blockIdx.x * 4 + (threadIdx.x >> 6);
  const int r = threadIdx.x & 63;
  float v = fire[(size_t)b * R_ + r];
  float m = v;
#pragma unroll
  for (int off = 32; off; off >>= 1) m = fmaxf(m, __shfl_xor(m, off, 64));
  float e = exp2f((v - m) * 1.4426950408889634f);
  float s = e;
#pragma unroll
  for (int off = 32; off; off >>= 1) s += __shfl_xor(s, off, 64);
  fire[(size_t)b * R_ + r] = e / s;
}

// ---------------- fused rule-GEMM: W-resident LDS, A-frags from global ----------------
// Grid 256 = 16 rg x 16 batch partitions (XCD swizzle: xcd owns 2 rgs -> 1 MB W in L2).
// Per block: 4 rules, 256 rows. W staged per (rule, kc-half) = 64 KB, double-buffered
// (2x64 KB LDS), linear global_load_lds (no swizzle; frag reads are lane-linear =
// conflict-free). A-frags read directly from global xf (contiguous 1 KB/wave, L2-hit).
// Per wave: 2 m-tiles x full N=128 (8 nt). 8 phases, one __syncthreads each.
// Staged volume: W 128 MB + xf 256 MB (both L2-resident) vs 512 MB fabric-bound before.
__global__ __launch_bounds__(512) void gemm_kernel(
    const unsigned short* __restrict__ xf, const unsigned short* __restrict__ wf,
    const float* __restrict__ fire, const float* __restrict__ bias,
    float* __restrict__ out) {
  __shared__ __align__(16) unsigned short w_s[2][32768];   // 2 x 64 KB
  __shared__ float fire_s[256 * 4];                        // 4 KB
  __shared__ float bias_s[4 * 128];                        // 2 KB

  const int tid = threadIdx.x;       // 0..511
  const int f = blockIdx.x;          // 0..255
  const int xcd = f & 7;
  const int idx = f >> 3;            // 0..31
  const int rg = 2 * xcd + (idx & 1);  // 0..15
  const int p = idx >> 1;            // 0..15 batch partition (256 rows)
  const int b0 = p * 256;

  const int wid = tid >> 6, lane = tid & 63;
  const int l16 = lane & 15, lhi = lane >> 4;
  const int mtG0 = p * 16 + wid * 2;       // global m-tile ids for this wave
  const int mtG1 = mtG0 + 1;

  const unsigned short* wrg = wf + (size_t)(rg * 4) * (8 * 16 * 512);

  // stage fire (256x4) and bias (4x128)
  {
#pragma unroll
    for (int q = 0; q < 2; ++q) {
      int t = q * 512 + tid;               // 0..1023
      fire_s[t] = fire[(size_t)(b0 + (t >> 2)) * R_ + rg * 4 + (t & 3)];
    }
    bias_s[tid & 511] = bias[rg * 4 * C_ + (tid & 511)];
  }

  // W stage: (rule RR, kc-half HL) -> w_s[BUF]; 4096 16B-chunks, 8 per thread.
  // chunk c: nt = c>>9, kco = c&511; dst linear c*8.
#define STAGE_W(RR, HL, BUF)                                                   \
  do {                                                                         \
    const unsigned short* ws_ = wrg + (size_t)(RR) * (8 * 16 * 512) + (HL) * (8 * 512); \
    _Pragma("unroll")                                                          \
    for (int q = 0; q < 8; ++q) {                                              \
      int c = q * 512 + tid;                                                   \
      const unsigned short* src = ws_ + (size_t)(c >> 9) * (16 * 512) + (c & 511) * 8; \
      __builtin_amdgcn_global_load_lds(                                        \
          (const __attribute__((address_space(1))) void*)src,                  \
          (__attribute__((address_space(3))) void*)(w_s[BUF] + c * 8), 16, 0, 0); \
    }                                                                          \
  } while (0)

  // compute one kc-half (HL literal): 8 kcl x { 2 global A-frags, 8 LDS B-frags, 16 MFMA }
#define COMP_HALF(HL)                                                          \
  do {                                                                         \
    _Pragma("unroll")                                                          \
    for (int kcl = 0; kcl < 8; ++kcl) {                                        \
      bf16x8 av0 = *reinterpret_cast<const bf16x8*>(                           \
          xf + ((size_t)(mtG0 * 16 + (HL) * 8 + kcl)) * 512 + lane * 8);       \
      bf16x8 av1 = *reinterpret_cast<const bf16x8*>(                           \
          xf + ((size_t)(mtG1 * 16 + (HL) * 8 + kcl)) * 512 + lane * 8);       \
      bf16x8 bv[8];                                                            \
      _Pragma("unroll") for (int nt = 0; nt < 8; ++nt)                         \
        bv[nt] = *reinterpret_cast<const bf16x8*>(                             \
            &w_s[HL][(nt * 8 + kcl) * 512 + lane * 8]);                        \
      _Pragma("unroll") for (int nt = 0; nt < 8; ++nt) {                       \
        acc0[nt] = __builtin_amdgcn_mfma_f32_16x16x32_bf16(av0, bv[nt], acc0[nt], 0, 0, 0); \
        acc1[nt] = __builtin_amdgcn_mfma_f32_16x16x32_bf16(av1, bv[nt], acc1[nt], 0, 0, 0); \
      }                                                                        \
    }                                                                          \
  } while (0)

  float tot0[8][4], tot1[8][4];
#pragma unroll
  for (int nt = 0; nt < 8; ++nt)
#pragma unroll
    for (int j = 0; j < 4; ++j) { tot0[nt][j] = 0.f; tot1[nt][j] = 0.f; }

  f32x4 acc0[8], acc1[8];

  // prologue: stage (r=0, h=0) into buf0
  STAGE_W(0, 0, 0);
  __syncthreads();

  for (int r = 0; r < 4; ++r) {
#pragma unroll
    for (int nt = 0; nt < 8; ++nt) {
      acc0[nt] = f32x4{0.f, 0.f, 0.f, 0.f};
      acc1[nt] = f32x4{0.f, 0.f, 0.f, 0.f};
    }
    // ---- phase h=0 (buf0): stage (r, h=1) -> buf1, compute half 0
    STAGE_W(r, 1, 1);
    COMP_HALF(0);
    __syncthreads();
    // ---- phase h=1 (buf1): stage (r+1, h=0) -> buf0, compute half 1
    if (r < 3) STAGE_W(r + 1, 0, 0);
    COMP_HALF(1);
    // rule epilogue: relu(+bias) * fire into tot (acc-only, no LDS deps on w_s)
#pragma unroll
    for (int nt = 0; nt < 8; ++nt) {
      int col = nt * 16 + l16;
      float bi = bias_s[r * 128 + col];
#pragma unroll
      for (int j = 0; j < 4; ++j) {
        int row0 = (wid * 2) * 16 + lhi * 4 + j;       // local rows 0..255
        int row1 = row0 + 16;
        float v0 = fmaxf(acc0[nt][j] + bi, 0.f);
        float v1 = fmaxf(acc1[nt][j] + bi, 0.f);
        tot0[nt][j] += v0 * fire_s[row0 * 4 + r];
        tot1[nt][j] += v1 * fire_s[row1 * 4 + r];
      }
    }
    __syncthreads();
  }

#undef STAGE_W
#undef COMP_HALF

#pragma unroll
  for (int nt = 0; nt < 8; ++nt) {
    int col = nt * 16 + l16;
#pragma unroll
    for (int j = 0; j < 4; ++j) {
      int row0 = b0 + (wid * 2) * 16 + lhi * 4 + j;
      atomicAdd(&out[(size_t)row0 * C_ + col], tot0[nt][j]);
      atomicAdd(&out[(size_t)(row0 + 16) * C_ + col], tot1[nt][j]);
    }
  }
}

extern "C" void kernel_launch(void* const* d_in, const int* in_sizes, int n_in,
                              void* d_out, int out_size, void* d_ws, size_t ws_size,
                              hipStream_t stream) {
  const float* x     = (const float*)d_in[0];
  const float* proto = (const float*)d_in[1];
  const float* var   = (const float*)d_in[2];
  const float* W     = (const float*)d_in[3];
  const float* bias  = (const float*)d_in[4];
  float* out  = (float*)d_out;
  float* fire = out + (size_t)B_ * C_;   // second output region (also fs_ini accumulator)

  const size_t WS_XF = (size_t)B_ * D_ * sizeof(unsigned short);       // 4 MiB frag-x
  const size_t WS_WF = (size_t)R_ * C_ * D_ * sizeof(unsigned short);  // 8 MiB frag-W
  const size_t WS_PS = (size_t)R_ * D_ * 2 * sizeof(float);            // 256 KiB
  if (ws_size < WS_XF + WS_WF + WS_PS) return;  // insufficient scratch -> visible failure

  unsigned short* xfp = (unsigned short*)d_ws;
  unsigned short* wfp = (unsigned short*)((char*)d_ws + WS_XF);
  float*          ps  = (float*)((char*)d_ws + WS_XF + WS_WF);

  // zero BOTH output regions: out accumulates gemm atomics, fire accumulates fs partials
  hipMemsetAsync(d_out, 0, (size_t)out_size * sizeof(float), stream);
  prep_wf_kernel<<<dim3(16, 64), dim3(256), 0, stream>>>(W, wfp);
  prep_ps_kernel<<<dim3(R_ * D_ / 256), dim3(256), 0, stream>>>(proto, var, ps);
  fs_partial_kernel<<<dim3(B_ / 16, 8), dim3(256), 0, stream>>>(x, ps, fire, xfp);
  softmax_kernel<<<dim3(B_ / 4), dim3(256), 0, stream>>>(fire);
  gemm_kernel<<<dim3(256), dim3(512), 0, stream>>>(xfp, wfp, fire, bias, out);
}

// Round 17
// 118.320 us; speedup vs baseline: 1.9402x; 1.2410x over previous
//
#include <hip/hip_runtime.h>
#include <hip/hip_bf16.h>
#include <cmath>

#define R_ 64
#define B_ 4096
#define D_ 512
#define C_ 128

typedef __attribute__((ext_vector_type(8))) short bf16x8;
typedef __attribute__((ext_vector_type(4))) float f32x4;

__device__ __forceinline__ unsigned short f2bf(float f) {
  union { float f; unsigned u; } x; x.f = f;
  unsigned r = (x.u + 0x7FFFu + ((x.u >> 16) & 1u)) >> 16;
  return (unsigned short)r;
}

// ---------------- prep: W[r][d][c] f32 -> W^T[r][c][d] bf16 ----------------
__global__ void prep_w_kernel(const float* __restrict__ W, unsigned short* __restrict__ wt) {
  __shared__ float t[32][33];
  int bx = blockIdx.x;
  int r = bx >> 6;
  int rem = bx & 63;
  int d0 = (rem >> 2) << 5;   // 16 d-tiles of 32
  int c0 = (rem & 3) << 5;    // 4 c-tiles of 32
  int tx = threadIdx.x & 31, ty = threadIdx.x >> 5;  // 32 x 8
  const float* Wr = W + (size_t)r * D_ * C_;
#pragma unroll
  for (int q = 0; q < 4; ++q) {
    int dl = q * 8 + ty;
    t[dl][tx] = Wr[(size_t)(d0 + dl) * C_ + c0 + tx];
  }
  __syncthreads();
  unsigned short* wtr = wt + (size_t)r * C_ * D_;
#pragma unroll
  for (int q = 0; q < 4; ++q) {
    int cl = q * 8 + ty;
    float v = t[tx][cl];                         // transposed read, pad-33 conflict-free
    wtr[(size_t)(c0 + cl) * D_ + d0 + tx] = f2bf(v);
  }
}

// ---------------- prep: (s, -p*s) per (rule, dim) ----------------
__global__ void prep_ps_kernel(const float* __restrict__ proto, const float* __restrict__ var,
                               float* __restrict__ ps) {
  int i = blockIdx.x * 256 + threadIdx.x;          // R*D elements
  float v = fminf(fmaxf(var[i], 1e-4f), 0.1f);
  float s = 1.2011224087864498f / v;
  float2 o; o.x = s; o.y = -proto[i] * s;
  reinterpret_cast<float2*>(ps)[i] = o;
}

// ---------------- antecedent partial + fused x->bf16 emission ----------------
__global__ __launch_bounds__(256, 4) void fs_partial_kernel(
    const float* __restrict__ x, const float* __restrict__ ps,
    float* __restrict__ fire, unsigned short* __restrict__ xw) {
  __shared__ float x_s[16 * 68];
  __shared__ __align__(16) float ps_s[64 * 128];   // [rule][dim*2], XOR-swizzled granules
  const int tid = threadIdx.x;
  const int b0 = blockIdx.x * 16;
  const int dq = blockIdx.y;                       // dims dq*64 .. dq*64+63

  {  // stage x tile: 16 rows x 64 dims
    int row = tid >> 4, c4 = tid & 15;
    float4 v = *reinterpret_cast<const float4*>(&x[(size_t)(b0 + row) * D_ + dq * 64 + c4 * 4]);
    *reinterpret_cast<float4*>(&x_s[row * 68 + c4 * 4]) = v;
  }
#pragma unroll
  for (int k = 0; k < 8; ++k) {  // stage ps tile: 64 rules x 32 granules(16B), swizzled
    int g = tid + k * 256;
    int row = g >> 5, gi = g & 31;
    float4 v = *reinterpret_cast<const float4*>(&ps[(size_t)row * (D_ * 2) + dq * 128 + gi * 4]);
    int gs = gi ^ (row & 31);
    *reinterpret_cast<float4*>((char*)ps_s + row * 512 + (gs << 4)) = v;
  }
  __syncthreads();

  {  // fused prep_x: emit bf16 of this block's x tile (disjoint across grid)
    int row = tid >> 4, c0 = (tid & 15) * 4;
    const float* sp = &x_s[row * 68 + c0];
    ushort4 o;
    o.x = f2bf(sp[0]); o.y = f2bf(sp[1]); o.z = f2bf(sp[2]); o.w = f2bf(sp[3]);
    *reinterpret_cast<ushort4*>(&xw[(size_t)(b0 + row) * D_ + dq * 64 + c0]) = o;
  }

  const int tr = tid & 63;   // rule = lane
  const int tb = tid >> 6;   // wave -> 4 batch rows
  const int s31 = tr & 31;
  const char* pb = (const char*)ps_s + tr * 512;
  float facc[4] = {0.f, 0.f, 0.f, 0.f};

#pragma unroll
  for (int d4 = 0; d4 < 16; ++d4) {
    float4 psa = *reinterpret_cast<const float4*>(pb + ((((d4 * 2) ^ s31)) << 4));
    float4 psb = *reinterpret_cast<const float4*>(pb + ((((d4 * 2 + 1) ^ s31)) << 4));
#pragma unroll
    for (int i = 0; i < 4; ++i) {
      float4 xv = *reinterpret_cast<const float4*>(&x_s[(tb * 4 + i) * 68 + d4 * 4]);
      float u0 = fmaf(xv.x, psa.x, psa.y);
      float u1 = fmaf(xv.y, psa.z, psa.w);
      float u2 = fmaf(xv.z, psb.x, psb.y);
      float u3 = fmaf(xv.w, psb.z, psb.w);
      facc[i] += exp2f(-(u0 * u0)) + exp2f(-(u1 * u1)) +
                 exp2f(-(u2 * u2)) + exp2f(-(u3 * u3));
    }
  }
#pragma unroll
  for (int i = 0; i < 4; ++i)
    atomicAdd(&fire[(size_t)(b0 + tb * 4 + i) * R_ + tr], facc[i]);
}

// ---------------- softmax over rules, in place on fire buffer ----------------
__global__ void softmax_kernel(float* __restrict__ fire) {
  const int b = blockIdx.x * 4 + (threadIdx.x >> 6);
  const int r = threadIdx.x & 63;
  float v = fire[(size_t)b * R_ + r];
  float m = v;
#pragma unroll
  for (int off = 32; off; off >>= 1) m = fmaxf(m, __shfl_xor(m, off, 64));
  float e = exp2f((v - m) * 1.4426950408889634f);
  float s = e;
#pragma unroll
  for (int off = 32; off; off >>= 1) s += __shfl_xor(s, off, 64);
  fire[(size_t)b * R_ + r] = e / s;
}

// ---------------- fused rule-GEMM + relu + fire-weighted combine ----------------
// R13 reg-staging body (67 us), single change: 2D XCD tiling. Each XCD owns a
// (4 rg x 16 bm) tile -> per-XCD working set = W 2 MB + A 2 MB = 4 MB = L2 size
// (R12's 1D swizzle gave 2 rg x 32 bm = 1+4 = 5 MB > L2 -> thrash -> null).
// BM=128, BN=C=128, BK=64, 4 rules/block. 8 waves (2x4), wave tile 64x32.
__global__ __launch_bounds__(512, 4) void gemm_kernel(
    const unsigned short* __restrict__ xw, const unsigned short* __restrict__ wt,
    const float* __restrict__ fire, const float* __restrict__ bias,
    float* __restrict__ out) {
  __shared__ __align__(16) unsigned short x_s[2][128 * 64];   // 2 x 16 KB
  __shared__ __align__(16) unsigned short w_s[2][128 * 64];   // 2 x 16 KB
  __shared__ float fire_s[128 * 4];
  __shared__ float bias_s[4 * 128];

  const int tid = threadIdx.x;       // 0..511
  // 2D XCD tile decode: xcd -> (rgG 0..3, bmG 0..1); idx -> (4 rgs x 16 bms)
  const int f = blockIdx.x;          // 0..511
  const int xcd = f & 7;
  const int idx = f >> 3;            // 0..63
  const int rg = (xcd >> 1) * 4 + (idx & 3);    // 0..15
  const int bm = (xcd & 1) * 16 + (idx >> 2);   // 0..31
  const int b0 = bm * 128;

  {
    int row = tid >> 2, g = tid & 3;
    fire_s[tid] = fire[(size_t)(b0 + row) * R_ + rg * 4 + g];
    bias_s[tid] = bias[rg * 4 * C_ + tid];
  }

  const int wid = tid >> 6, lane = tid & 63;
  const int wm = wid >> 2, wn = wid & 3;           // 2 x 4 wave grid, wave tile 64x32
  const int l16 = lane & 15, lhi = lane >> 4;

  // ds_read byte offsets (XOR-swizzled 16B granules within 128B rows)
  int offA[4][2], offB[2][2];
#pragma unroll
  for (int m = 0; m < 4; ++m) {
    int row = wm * 64 + m * 16 + l16;              // 0..127
#pragma unroll
    for (int ks = 0; ks < 2; ++ks)
      offA[m][ks] = row * 128 + (((ks * 4 + lhi) ^ (row & 7)) << 4);
  }
#pragma unroll
  for (int n = 0; n < 2; ++n) {
    int row = wn * 32 + n * 16 + l16;              // 0..127
#pragma unroll
    for (int ks = 0; ks < 2; ++ks)
      offB[n][ks] = row * 128 + (((ks * 4 + lhi) ^ (row & 7)) << 4);
  }

  // staging chunk maps: 1024 chunks each for A and B; 2 per thread each.
  // global offset LINEAR, LDS dest swizzled.
  int a_goff[2], a_ldst[2], b_goff[2], b_ldst[2];
#pragma unroll
  for (int q = 0; q < 2; ++q) {
    int ch = q * 512 + tid;
    int row = ch >> 3, g = ch & 7;
    a_goff[q] = row * D_ + g * 8;
    a_ldst[q] = row * 128 + ((g ^ (row & 7)) << 4);
    b_goff[q] = row * D_ + g * 8;
    b_ldst[q] = row * 128 + ((g ^ (row & 7)) << 4);
  }

  const unsigned short* xsrc = xw + (size_t)b0 * D_;
  const unsigned short* wbase = wt + (size_t)(rg * 4) * C_ * D_;

  float tot[4][2][4];
#pragma unroll
  for (int m = 0; m < 4; ++m)
#pragma unroll
    for (int n = 0; n < 2; ++n)
#pragma unroll
      for (int j = 0; j < 4; ++j) tot[m][n][j] = 0.f;

  f32x4 acc[4][2];

  // prologue: stage tile 0 via regs
  {
    uint4 la[2], lb[2];
#pragma unroll
    for (int q = 0; q < 2; ++q) {
      la[q] = *reinterpret_cast<const uint4*>(xsrc + a_goff[q]);
      lb[q] = *reinterpret_cast<const uint4*>(wbase + b_goff[q]);
    }
#pragma unroll
    for (int q = 0; q < 2; ++q) {
      *reinterpret_cast<uint4*>((char*)x_s[0] + a_ldst[q]) = la[q];
      *reinterpret_cast<uint4*>((char*)w_s[0] + b_ldst[q]) = lb[q];
    }
  }
  __syncthreads();

  int cur = 0;
  for (int s = 0; s < 32; ++s) {
    const int g = s >> 3, kk = s & 7;
    if (kk == 0) {
#pragma unroll
      for (int m = 0; m < 4; ++m)
#pragma unroll
        for (int n = 0; n < 2; ++n)
          acc[m][n] = f32x4{0.f, 0.f, 0.f, 0.f};
    }
    // issue next tile's global loads early (overlap with ds_read+MFMA below)
    uint4 la[2], lb[2];
    if (s + 1 < 32) {
      const int s1 = s + 1;
      const unsigned short* xs1 = xsrc + (s1 & 7) * 64;
      const unsigned short* ws1 = wbase + (size_t)(s1 >> 3) * C_ * D_ + (s1 & 7) * 64;
#pragma unroll
      for (int q = 0; q < 2; ++q) {
        la[q] = *reinterpret_cast<const uint4*>(xs1 + a_goff[q]);
        lb[q] = *reinterpret_cast<const uint4*>(ws1 + b_goff[q]);
      }
    }
    const char* xb = (const char*)x_s[cur];
    const char* wb = (const char*)w_s[cur];
#pragma unroll
    for (int ks = 0; ks < 2; ++ks) {
      bf16x8 av[4], bv[2];
#pragma unroll
      for (int m = 0; m < 4; ++m)
        av[m] = *reinterpret_cast<const bf16x8*>(xb + offA[m][ks]);
#pragma unroll
      for (int n = 0; n < 2; ++n)
        bv[n] = *reinterpret_cast<const bf16x8*>(wb + offB[n][ks]);
#pragma unroll
      for (int m = 0; m < 4; ++m)
#pragma unroll
        for (int n = 0; n < 2; ++n)
          acc[m][n] = __builtin_amdgcn_mfma_f32_16x16x32_bf16(av[m], bv[n], acc[m][n], 0, 0, 0);
    }
    if (kk == 7) {  // rule g finished: relu(+bias) * fire, accumulate
#pragma unroll
      for (int m = 0; m < 4; ++m)
#pragma unroll
        for (int n = 0; n < 2; ++n) {
          int col = wn * 32 + n * 16 + l16;
          float bi = bias_s[g * 128 + col];
#pragma unroll
          for (int j = 0; j < 4; ++j) {
            int rowl = wm * 64 + m * 16 + lhi * 4 + j;
            float v = acc[m][n][j] + bi;
            v = fmaxf(v, 0.f);
            tot[m][n][j] += v * fire_s[rowl * 4 + g];
          }
        }
    }
    if (s + 1 < 32) {
      // compiler inserts vmcnt waits on la/lb use; writes target buf^1 whose
      // readers all passed the previous barrier.
#pragma unroll
      for (int q = 0; q < 2; ++q) {
        *reinterpret_cast<uint4*>((char*)x_s[cur ^ 1] + a_ldst[q]) = la[q];
        *reinterpret_cast<uint4*>((char*)w_s[cur ^ 1] + b_ldst[q]) = lb[q];
      }
    }
    __syncthreads();
    cur ^= 1;
  }

#pragma unroll
  for (int m = 0; m < 4; ++m)
#pragma unroll
    for (int n = 0; n < 2; ++n) {
      int col = wn * 32 + n * 16 + l16;
#pragma unroll
      for (int j = 0; j < 4; ++j) {
        int rowl = wm * 64 + m * 16 + lhi * 4 + j;
        atomicAdd(&out[(size_t)(b0 + rowl) * C_ + col], tot[m][n][j]);
      }
    }
}

extern "C" void kernel_launch(void* const* d_in, const int* in_sizes, int n_in,
                              void* d_out, int out_size, void* d_ws, size_t ws_size,
                              hipStream_t stream) {
  const float* x     = (const float*)d_in[0];
  const float* proto = (const float*)d_in[1];
  const float* var   = (const float*)d_in[2];
  const float* W     = (const float*)d_in[3];
  const float* bias  = (const float*)d_in[4];
  float* out  = (float*)d_out;
  float* fire = out + (size_t)B_ * C_;   // second output region (also fs_ini accumulator)

  const size_t WS_X  = (size_t)B_ * D_ * sizeof(unsigned short);       // 4 MiB
  const size_t WS_WT = (size_t)R_ * C_ * D_ * sizeof(unsigned short);  // 8 MiB
  const size_t WS_PS = (size_t)R_ * D_ * 2 * sizeof(float);            // 256 KiB
  if (ws_size < WS_X + WS_WT + WS_PS) return;  // insufficient scratch -> visible failure

  unsigned short* xw  = (unsigned short*)d_ws;
  unsigned short* wtp = (unsigned short*)((char*)d_ws + WS_X);
  float*          ps  = (float*)((char*)d_ws + WS_X + WS_WT);

  // zero BOTH output regions: out accumulates gemm atomics, fire accumulates fs partials
  hipMemsetAsync(d_out, 0, (size_t)out_size * sizeof(float), stream);
  prep_w_kernel<<<dim3(R_ * 64), dim3(256), 0, stream>>>(W, wtp);
  prep_ps_kernel<<<dim3(R_ * D_ / 256), dim3(256), 0, stream>>>(proto, var, ps);
  fs_partial_kernel<<<dim3(B_ / 16, 8), dim3(256), 0, stream>>>(x, ps, fire, xw);
  softmax_kernel<<<dim3(B_ / 4), dim3(256), 0, stream>>>(fire);
  gemm_kernel<<<dim3(512), dim3(512), 0, stream>>>(xw, wtp, fire, bias, out);
}